// Round 1
// baseline (656.895 us; speedup 1.0000x reference)
//
#include <hip/hip_runtime.h>

#define BB 64
#define TT 512
#define DD 1024
#define UU 128

// ---------------------------------------------------------------------------
// Kernel 1: logits = inputs(32768x1024) @ kernel(1024x128) + bias   (fp32)
// Tile: BM=64 rows x N=128 cols x BK=64. 256 threads, 4x8 outputs/thread.
// ---------------------------------------------------------------------------
#define GBM 64
#define GBK 64

__global__ __launch_bounds__(256) void gemm_kernel(const float* __restrict__ A,
                                                   const float* __restrict__ W,
                                                   const float* __restrict__ bias,
                                                   float* __restrict__ C) {
    __shared__ __align__(16) float As[GBK][GBM + 4];  // k-major, padded
    __shared__ __align__(16) float Ws[GBK][UU];       // k-major

    const int tid = threadIdx.x;
    const int mi = tid >> 4;   // 0..15
    const int ni = tid & 15;   // 0..15
    const int row0 = blockIdx.x * GBM;

    float acc[4][8];
#pragma unroll
    for (int i = 0; i < 4; ++i)
#pragma unroll
        for (int j = 0; j < 8; ++j) acc[i][j] = 0.0f;

    for (int k0 = 0; k0 < DD; k0 += GBK) {
        // stage A tile (transpose to k-major): 64 rows x 64 k
        {
            const int c_ = tid & 15;   // k-quad
            const int r_ = tid >> 4;   // row base
#pragma unroll
            for (int p = 0; p < 4; ++p) {
                const int r = r_ + p * 16;
                const float4 a4 = *(const float4*)&A[(size_t)(row0 + r) * DD + k0 + c_ * 4];
                As[c_ * 4 + 0][r] = a4.x;
                As[c_ * 4 + 1][r] = a4.y;
                As[c_ * 4 + 2][r] = a4.z;
                As[c_ * 4 + 3][r] = a4.w;
            }
            // stage W tile: 64 k x 128 n (same layout as global, vectorized)
            const int n4 = (tid & 31) * 4;
            const int kk = tid >> 5;   // 0..7
#pragma unroll
            for (int q = 0; q < 8; ++q) {
                *(float4*)&Ws[kk + q * 8][n4] =
                    *(const float4*)&W[(size_t)(k0 + kk + q * 8) * UU + n4];
            }
        }
        __syncthreads();

#pragma unroll 8
        for (int k = 0; k < GBK; ++k) {
            const float4 av = *(const float4*)&As[k][mi * 4];
            const float4 w0 = *(const float4*)&Ws[k][ni * 8];
            const float4 w1 = *(const float4*)&Ws[k][ni * 8 + 4];
            const float a[4] = {av.x, av.y, av.z, av.w};
            const float w[8] = {w0.x, w0.y, w0.z, w0.w, w1.x, w1.y, w1.z, w1.w};
#pragma unroll
            for (int i = 0; i < 4; ++i)
#pragma unroll
                for (int j = 0; j < 8; ++j) acc[i][j] = fmaf(a[i], w[j], acc[i][j]);
        }
        __syncthreads();
    }

    // epilogue: + bias, store
    const float4 b0 = *(const float4*)&bias[ni * 8];
    const float4 b1 = *(const float4*)&bias[ni * 8 + 4];
#pragma unroll
    for (int i = 0; i < 4; ++i) {
        const int row = row0 + mi * 4 + i;
        float4 o0, o1;
        o0.x = acc[i][0] + b0.x; o0.y = acc[i][1] + b0.y;
        o0.z = acc[i][2] + b0.z; o0.w = acc[i][3] + b0.w;
        o1.x = acc[i][4] + b1.x; o1.y = acc[i][5] + b1.y;
        o1.z = acc[i][6] + b1.z; o1.w = acc[i][7] + b1.w;
        *(float4*)&C[(size_t)row * UU + ni * 8] = o0;
        *(float4*)&C[(size_t)row * UU + ni * 8 + 4] = o1;
    }
}

// ---------------------------------------------------------------------------
// Kernel 2: Viterbi forward + backtrace, one block per batch.
// 256 threads: tid = u + 128*h, h in {0,1}. Thread holds chain[v][u] for
// v in [64h, 64h+64) in registers. Backpointers kept in LDS (u8).
// ---------------------------------------------------------------------------
__global__ __launch_bounds__(256) void viterbi_kernel(const float* __restrict__ logits,
                                                      const float* __restrict__ chain,
                                                      float* __restrict__ out) {
    __shared__ __align__(16) float state[2][UU];
    __shared__ float part_val[256];
    __shared__ int   part_arg[256];
    __shared__ unsigned char bp[(TT - 1) * UU];  // 65408 B
    __shared__ int tags_i[TT];

    const int b   = blockIdx.x;
    const int tid = threadIdx.x;
    const int u   = tid & (UU - 1);
    const int h   = tid >> 7;

    // chain column u, rows [64h, 64h+64) -> registers (coalesced loads over u)
    float cr[64];
#pragma unroll
    for (int j = 0; j < 64; ++j) cr[j] = chain[(size_t)((h << 6) + j) * UU + u];

    const float* lg = logits + (size_t)b * TT * UU;

    if (tid < UU) state[0][tid] = lg[tid];
    __syncthreads();

    int cur = 0;
    for (int t = 1; t < TT; ++t) {
        // prefetch pot (only h==0 consumes it; wave-uniform branch)
        float pot = 0.0f;
        if (h == 0) pot = lg[(size_t)t * UU + u];

        float best = -INFINITY;
        int   arg  = 0;
#pragma unroll
        for (int j0 = 0; j0 < 64; j0 += 4) {
            const float4 sv = *(const float4*)&state[cur][(h << 6) + j0];
            float s;
            s = sv.x + cr[j0 + 0]; if (s > best) { best = s; arg = j0 + 0; }
            s = sv.y + cr[j0 + 1]; if (s > best) { best = s; arg = j0 + 1; }
            s = sv.z + cr[j0 + 2]; if (s > best) { best = s; arg = j0 + 2; }
            s = sv.w + cr[j0 + 3]; if (s > best) { best = s; arg = j0 + 3; }
        }
        part_val[tid] = best;
        part_arg[tid] = arg + (h << 6);
        __syncthreads();

        if (h == 0) {
            const float v0 = part_val[u];
            const float v1 = part_val[u + 128];
            const int   a0 = part_arg[u];
            const int   a1 = part_arg[u + 128];
            float bv = v0; int ba = a0;
            if (v1 > v0) { bv = v1; ba = a1; }   // strict >: first-index tie-break
            state[cur ^ 1][u] = pot + bv;
            bp[(size_t)(t - 1) * UU + u] = (unsigned char)ba;
        }
        __syncthreads();
        cur ^= 1;
    }

    // final argmax + backtrace (serial, thread 0; all in LDS)
    if (tid == 0) {
        float bv = state[cur][0];
        int   bt = 0;
#pragma unroll 4
        for (int v = 1; v < UU; ++v) {
            const float s = state[cur][v];
            if (s > bv) { bv = s; bt = v; }
        }
        int tag = bt;
        tags_i[TT - 1] = tag;
        for (int i = TT - 2; i >= 0; --i) {
            tag = bp[(size_t)i * UU + tag];
            tags_i[i] = tag;
        }
    }
    __syncthreads();

    // write tags as float, coalesced
    for (int i = tid; i < TT; i += 256) {
        out[(size_t)b * TT + i] = (float)tags_i[i];
    }
}

extern "C" void kernel_launch(void* const* d_in, const int* in_sizes, int n_in,
                              void* d_out, int out_size, void* d_ws, size_t ws_size,
                              hipStream_t stream) {
    const float* inputs = (const float*)d_in[0];
    const float* kern   = (const float*)d_in[1];
    const float* bias   = (const float*)d_in[2];
    const float* chain  = (const float*)d_in[3];
    float* logits = (float*)d_ws;   // 32768*128*4 = 16.78 MB scratch
    float* out    = (float*)d_out;

    gemm_kernel<<<dim3((BB * TT) / GBM), dim3(256), 0, stream>>>(inputs, kern, bias, logits);
    viterbi_kernel<<<dim3(BB), dim3(256), 0, stream>>>(logits, chain, out);
}

// Round 2
// 510.321 us; speedup vs baseline: 1.2872x; 1.2872x over previous
//
#include <hip/hip_runtime.h>

#define BB 64
#define TT 512
#define DD 1024
#define UU 128

// ---------------------------------------------------------------------------
// Kernel 1: logits = inputs(32768x1024) @ kernel(1024x128) + bias   (fp32)
// ---------------------------------------------------------------------------
#define GBM 64
#define GBK 64

__global__ __launch_bounds__(256) void gemm_kernel(const float* __restrict__ A,
                                                   const float* __restrict__ W,
                                                   const float* __restrict__ bias,
                                                   float* __restrict__ C) {
    __shared__ __align__(16) float As[GBK][GBM + 4];  // k-major, padded
    __shared__ __align__(16) float Ws[GBK][UU];       // k-major

    const int tid = threadIdx.x;
    const int mi = tid >> 4;   // 0..15
    const int ni = tid & 15;   // 0..15
    const int row0 = blockIdx.x * GBM;

    float acc[4][8];
#pragma unroll
    for (int i = 0; i < 4; ++i)
#pragma unroll
        for (int j = 0; j < 8; ++j) acc[i][j] = 0.0f;

    for (int k0 = 0; k0 < DD; k0 += GBK) {
        {
            const int c_ = tid & 15;
            const int r_ = tid >> 4;
#pragma unroll
            for (int p = 0; p < 4; ++p) {
                const int r = r_ + p * 16;
                const float4 a4 = *(const float4*)&A[(size_t)(row0 + r) * DD + k0 + c_ * 4];
                As[c_ * 4 + 0][r] = a4.x;
                As[c_ * 4 + 1][r] = a4.y;
                As[c_ * 4 + 2][r] = a4.z;
                As[c_ * 4 + 3][r] = a4.w;
            }
            const int n4 = (tid & 31) * 4;
            const int kk = tid >> 5;
#pragma unroll
            for (int q = 0; q < 8; ++q) {
                *(float4*)&Ws[kk + q * 8][n4] =
                    *(const float4*)&W[(size_t)(k0 + kk + q * 8) * UU + n4];
            }
        }
        __syncthreads();

#pragma unroll 8
        for (int k = 0; k < GBK; ++k) {
            const float4 av = *(const float4*)&As[k][mi * 4];
            const float4 w0 = *(const float4*)&Ws[k][ni * 8];
            const float4 w1 = *(const float4*)&Ws[k][ni * 8 + 4];
            const float a[4] = {av.x, av.y, av.z, av.w};
            const float w[8] = {w0.x, w0.y, w0.z, w0.w, w1.x, w1.y, w1.z, w1.w};
#pragma unroll
            for (int i = 0; i < 4; ++i)
#pragma unroll
                for (int j = 0; j < 8; ++j) acc[i][j] = fmaf(a[i], w[j], acc[i][j]);
        }
        __syncthreads();
    }

    const float4 b0 = *(const float4*)&bias[ni * 8];
    const float4 b1 = *(const float4*)&bias[ni * 8 + 4];
#pragma unroll
    for (int i = 0; i < 4; ++i) {
        const int row = row0 + mi * 4 + i;
        float4 o0, o1;
        o0.x = acc[i][0] + b0.x; o0.y = acc[i][1] + b0.y;
        o0.z = acc[i][2] + b0.z; o0.w = acc[i][3] + b0.w;
        o1.x = acc[i][4] + b1.x; o1.y = acc[i][5] + b1.y;
        o1.z = acc[i][6] + b1.z; o1.w = acc[i][7] + b1.w;
        *(float4*)&C[(size_t)row * UU + ni * 8] = o0;
        *(float4*)&C[(size_t)row * UU + ni * 8 + 4] = o1;
    }
}

// ---------------------------------------------------------------------------
// Kernel 2: Viterbi. One block (512 threads) per batch.
// tid -> (u = tid>>2, h = tid&3). Lane handles v in [32h, 32h+32).
// The 4 lanes of a u are adjacent in one wave -> shfl_xor combine, 1 barrier/step.
// State padded v -> v + 4*(v>>5) so the 4 h-chunks hit distinct LDS banks.
// Backpointers packed 4 steps per u32. Segmented parallel backtrace (8x64).
// ---------------------------------------------------------------------------
__device__ __forceinline__ int SP(int v) { return v + ((v >> 5) << 2); }

__global__ __launch_bounds__(512) void viterbi_kernel(const float* __restrict__ logits,
                                                      const float* __restrict__ chain,
                                                      float* __restrict__ out) {
    __shared__ __align__(16) float st[2][144];
    __shared__ unsigned int bp32[128 * UU];      // 64 KB: [ (t-1)>>2 ][ u ], byte (t-1)&3
    __shared__ unsigned char segmap[8][128];
    __shared__ int entryT[8];
    __shared__ int tags_i[TT];
    __shared__ int final_tag_s;

    const int b = blockIdx.x;
    const int tid = threadIdx.x;
    const int u = tid >> 2;
    const int h = tid & 3;

    // chain[v][u] for v in [32h, 32h+32) -> registers
    float cr[32];
#pragma unroll
    for (int j = 0; j < 32; ++j) cr[j] = chain[(size_t)(32 * h + j) * UU + u];

    const float* lg = logits + (size_t)b * TT * UU;

    if (tid < UU) st[0][SP(tid)] = lg[tid];
    float pot_next = lg[UU + u];           // pot for t=1 (h-duplicated, same cacheline)
    __syncthreads();

    unsigned int bpw = 0;
    int cur = 0;
    for (int t = 1; t < TT; ++t) {
        const float pot = pot_next;
        if (t + 1 < TT) pot_next = lg[(size_t)(t + 1) * UU + u];

        const float* sb = &st[cur][36 * h];   // 144h bytes: 16B-aligned, distinct banks per h
        float best = -INFINITY;
        int arg = 0;
#pragma unroll
        for (int j0 = 0; j0 < 32; j0 += 4) {
            const float4 sv = *(const float4*)&sb[j0];
            float s;
            s = sv.x + cr[j0 + 0]; if (s > best) { best = s; arg = 32 * h + j0 + 0; }
            s = sv.y + cr[j0 + 1]; if (s > best) { best = s; arg = 32 * h + j0 + 1; }
            s = sv.z + cr[j0 + 2]; if (s > best) { best = s; arg = 32 * h + j0 + 2; }
            s = sv.w + cr[j0 + 3]; if (s > best) { best = s; arg = 32 * h + j0 + 3; }
        }
        // combine the 4 h-lanes of this u (adjacent lanes, same wave)
#pragma unroll
        for (int d = 1; d <= 2; d <<= 1) {
            const float ov = __shfl_xor(best, d, 64);
            const int   oa = __shfl_xor(arg, d, 64);
            if (ov > best || (ov == best && oa < arg)) { best = ov; arg = oa; }
        }
        if (h == 0) {
            st[cur ^ 1][SP(u)] = pot + best;
            bpw |= (unsigned int)arg << (8 * ((t - 1) & 3));
            if (((t - 1) & 3) == 3) { bp32[((t - 1) >> 2) * UU + u] = bpw; bpw = 0; }
        }
        __syncthreads();
        cur ^= 1;
    }
    if (h == 0) bp32[127 * UU + u] = bpw;   // residual: transitions 508..510

    // final argmax (tie -> lowest index), first wave only
    if (tid < 64) {
        float bv = st[cur][SP(tid)];
        int bi = tid;
        const float v2 = st[cur][SP(tid + 64)];
        if (v2 > bv) { bv = v2; bi = tid + 64; }
#pragma unroll
        for (int d = 1; d < 64; d <<= 1) {
            const float ov = __shfl_xor(bv, d, 64);
            const int oi = __shfl_xor(bi, d, 64);
            if (ov > bv || (ov == bv && oi < bi)) { bv = ov; bi = oi; }
        }
        if (tid == 0) final_tag_s = bi;
    }
    __syncthreads();

    // ---- segmented backtrace: 8 segments of <=64 transitions ----
    // phase 1: segment maps (end tag at pos pend(s) -> tag at pos 64s), 1024 walks
    for (int w = tid; w < 8 * 128; w += 512) {
        const int seg = w >> 7;
        int tg = w & 127;
        const int pend = (seg == 7) ? (TT - 1) : 64 * (seg + 1);
        for (int p = pend; p > 64 * seg; --p) {
            const int i = p - 1;
            const unsigned int word = bp32[(i >> 2) * UU + tg];
            tg = (word >> (8 * (i & 3))) & 255u;
        }
        segmap[seg][w & 127] = (unsigned char)tg;
    }
    __syncthreads();

    // phase 2: stitch entry tags (entryT[s] = tag at position pend(s))
    if (tid == 0) {
        entryT[7] = final_tag_s;
        for (int s = 6; s >= 0; --s) entryT[s] = segmap[s + 1][entryT[s + 1]];
    }
    __syncthreads();

    // phase 3: 8 parallel path walks recording tags
    if (tid < 8) {
        const int seg = tid;
        int tg = entryT[seg];
        const int pend = (seg == 7) ? (TT - 1) : 64 * (seg + 1);
        if (seg == 7) tags_i[TT - 1] = tg;
        for (int p = pend; p > 64 * seg; --p) {
            const int i = p - 1;
            const unsigned int word = bp32[(i >> 2) * UU + tg];
            tg = (word >> (8 * (i & 3))) & 255u;
            tags_i[i] = tg;
        }
    }
    __syncthreads();

    out[(size_t)b * TT + tid] = (float)tags_i[tid];
}

extern "C" void kernel_launch(void* const* d_in, const int* in_sizes, int n_in,
                              void* d_out, int out_size, void* d_ws, size_t ws_size,
                              hipStream_t stream) {
    const float* inputs = (const float*)d_in[0];
    const float* kern   = (const float*)d_in[1];
    const float* bias   = (const float*)d_in[2];
    const float* chain  = (const float*)d_in[3];
    float* logits = (float*)d_ws;   // 16.78 MB scratch
    float* out    = (float*)d_out;

    gemm_kernel<<<dim3((BB * TT) / GBM), dim3(256), 0, stream>>>(inputs, kern, bias, logits);
    viterbi_kernel<<<dim3(BB), dim3(512), 0, stream>>>(logits, chain, out);
}

// Round 3
// 489.651 us; speedup vs baseline: 1.3416x; 1.0422x over previous
//
#include <hip/hip_runtime.h>

#define BB 64
#define TT 512
#define DD 1024
#define UU 128

// ---------------------------------------------------------------------------
// Kernel 1: logits = inputs(32768x1024) @ kernel(1024x128) + bias   (fp32)
// 256 blocks x 256 threads, tile 128x128, BK=32, 8x8 outputs/thread.
// ---------------------------------------------------------------------------
__global__ __launch_bounds__(256) void gemm_kernel(const float* __restrict__ A,
                                                   const float* __restrict__ W,
                                                   const float* __restrict__ bias,
                                                   float* __restrict__ C) {
    __shared__ float As[32][132];   // k-major; 132-pad keeps 16B row alignment
    __shared__ float Ws[32][132];

    const int tid = threadIdx.x;
    const int my = tid >> 4;        // 0..15
    const int nx = tid & 15;        // 0..15
    const int row0 = blockIdx.x * 128;

    float acc[8][8] = {};

    const int sc = tid & 7;         // k-quad 0..7
    const int sr = tid >> 3;        // row base 0..31
    const int wn = (tid & 31) * 4;  // n offset
    const int wk = tid >> 5;        // 0..7

    for (int k0 = 0; k0 < DD; k0 += 32) {
        // stage A (transpose to k-major): 128 rows x 32 k
#pragma unroll
        for (int p = 0; p < 4; ++p) {
            const int r = sr + p * 32;
            const float4 a4 = *(const float4*)&A[(size_t)(row0 + r) * DD + k0 + sc * 4];
            As[sc * 4 + 0][r] = a4.x;
            As[sc * 4 + 1][r] = a4.y;
            As[sc * 4 + 2][r] = a4.z;
            As[sc * 4 + 3][r] = a4.w;
        }
        // stage W: 32 k x 128 n (row-major, coalesced)
#pragma unroll
        for (int q = 0; q < 4; ++q) {
            *(float4*)&Ws[wk + 8 * q][wn] =
                *(const float4*)&W[(size_t)(k0 + wk + 8 * q) * UU + wn];
        }
        __syncthreads();

#pragma unroll 8
        for (int k = 0; k < 32; ++k) {
            const float4 av0 = *(const float4*)&As[k][my * 8];
            const float4 av1 = *(const float4*)&As[k][my * 8 + 4];
            const float4 wv0 = *(const float4*)&Ws[k][nx * 8];
            const float4 wv1 = *(const float4*)&Ws[k][nx * 8 + 4];
            const float a[8] = {av0.x, av0.y, av0.z, av0.w, av1.x, av1.y, av1.z, av1.w};
            const float w[8] = {wv0.x, wv0.y, wv0.z, wv0.w, wv1.x, wv1.y, wv1.z, wv1.w};
#pragma unroll
            for (int i = 0; i < 8; ++i)
#pragma unroll
                for (int j = 0; j < 8; ++j) acc[i][j] = fmaf(a[i], w[j], acc[i][j]);
        }
        __syncthreads();
    }

    const float4 b0 = *(const float4*)&bias[nx * 8];
    const float4 b1 = *(const float4*)&bias[nx * 8 + 4];
#pragma unroll
    for (int i = 0; i < 8; ++i) {
        const int row = row0 + my * 8 + i;
        float4 o0, o1;
        o0.x = acc[i][0] + b0.x; o0.y = acc[i][1] + b0.y;
        o0.z = acc[i][2] + b0.z; o0.w = acc[i][3] + b0.w;
        o1.x = acc[i][4] + b1.x; o1.y = acc[i][5] + b1.y;
        o1.z = acc[i][6] + b1.z; o1.w = acc[i][7] + b1.w;
        *(float4*)&C[(size_t)row * UU + nx * 8] = o0;
        *(float4*)&C[(size_t)row * UU + nx * 8 + 4] = o1;
    }
}

// ---------------------------------------------------------------------------
// Kernel 2: Viterbi. One block (512 threads) per batch.
// tid -> (u = tid>>2, h = tid&3), 32 v per lane. Inner max-argmax done as
// 4 independent chains of 8 (breaks the serial cmp chain), then 3 merges,
// then 2 shfl_xor levels across the 4 h-lanes. One barrier per step.
// ---------------------------------------------------------------------------
__device__ __forceinline__ int SP(int v) { return v + ((v >> 5) << 2); }

__global__ __launch_bounds__(512) void viterbi_kernel(const float* __restrict__ logits,
                                                      const float* __restrict__ chain,
                                                      float* __restrict__ out) {
    __shared__ __align__(16) float st[2][144];
    __shared__ unsigned int bp32[128 * UU];      // 64 KB
    __shared__ unsigned char segmap[8][128];
    __shared__ int entryT[8];
    __shared__ int tags_i[TT];
    __shared__ int final_tag_s;

    const int b = blockIdx.x;
    const int tid = threadIdx.x;
    const int u = tid >> 2;
    const int h = tid & 3;

    float cr[32];
#pragma unroll
    for (int j = 0; j < 32; ++j) cr[j] = chain[(size_t)(32 * h + j) * UU + u];

    const float* lg = logits + (size_t)b * TT * UU;

    if (tid < UU) st[0][SP(tid)] = lg[tid];
    float pot_next = lg[UU + u];
    __syncthreads();

    unsigned int bpw = 0;
    int cur = 0;
    for (int t = 1; t < TT; ++t) {
        const float pot = pot_next;
        if (t + 1 < TT) pot_next = lg[(size_t)(t + 1) * UU + u];

        const float* sb = &st[cur][36 * h];
        float s[32];
#pragma unroll
        for (int q = 0; q < 8; ++q) {
            const float4 sv = *(const float4*)&sb[4 * q];
            s[4 * q + 0] = sv.x + cr[4 * q + 0];
            s[4 * q + 1] = sv.y + cr[4 * q + 1];
            s[4 * q + 2] = sv.z + cr[4 * q + 2];
            s[4 * q + 3] = sv.w + cr[4 * q + 3];
        }
        // 4 independent (best,arg) chains over contiguous ranges
        float bv0 = s[0], bv1 = s[8], bv2 = s[16], bv3 = s[24];
        int   ba0 = 0,    ba1 = 8,    ba2 = 16,   ba3 = 24;
#pragma unroll
        for (int i = 1; i < 8; ++i) {
            const bool g0 = s[i]      > bv0; bv0 = g0 ? s[i]      : bv0; ba0 = g0 ? i      : ba0;
            const bool g1 = s[8 + i]  > bv1; bv1 = g1 ? s[8 + i]  : bv1; ba1 = g1 ? 8 + i  : ba1;
            const bool g2 = s[16 + i] > bv2; bv2 = g2 ? s[16 + i] : bv2; ba2 = g2 ? 16 + i : ba2;
            const bool g3 = s[24 + i] > bv3; bv3 = g3 ? s[24 + i] : bv3; ba3 = g3 ? 24 + i : ba3;
        }
        // merges: higher-index chain wins only on strict > (keeps lowest index)
        const bool gA = bv1 > bv0; const float bvA = gA ? bv1 : bv0; const int baA = gA ? ba1 : ba0;
        const bool gB = bv3 > bv2; const float bvB = gB ? bv3 : bv2; const int baB = gB ? ba3 : ba2;
        const bool gC = bvB > bvA; float best  = gC ? bvB : bvA; int argl = gC ? baB : baA;
        int arg = 32 * h + argl;

#pragma unroll
        for (int d = 1; d <= 2; d <<= 1) {
            const float ov = __shfl_xor(best, d, 64);
            const int   oa = __shfl_xor(arg, d, 64);
            const bool take = (ov > best) || (ov == best && oa < arg);
            best = take ? ov : best;
            arg  = take ? oa : arg;
        }
        if (h == 0) {
            st[cur ^ 1][SP(u)] = pot + best;
            bpw |= (unsigned int)arg << (8 * ((t - 1) & 3));
            if (((t - 1) & 3) == 3) { bp32[((t - 1) >> 2) * UU + u] = bpw; bpw = 0; }
        }
        __syncthreads();
        cur ^= 1;
    }
    if (h == 0) bp32[127 * UU + u] = bpw;   // transitions 508..510

    // final argmax (tie -> lowest index), first wave only
    if (tid < 64) {
        float bv = st[cur][SP(tid)];
        int bi = tid;
        const float v2 = st[cur][SP(tid + 64)];
        if (v2 > bv) { bv = v2; bi = tid + 64; }
#pragma unroll
        for (int d = 1; d < 64; d <<= 1) {
            const float ov = __shfl_xor(bv, d, 64);
            const int oi = __shfl_xor(bi, d, 64);
            if (ov > bv || (ov == bv && oi < bi)) { bv = ov; bi = oi; }
        }
        if (tid == 0) final_tag_s = bi;
    }
    __syncthreads();

    // ---- segmented backtrace: 8 segments of <=64 transitions ----
    for (int w = tid; w < 8 * 128; w += 512) {
        const int seg = w >> 7;
        int tg = w & 127;
        const int pend = (seg == 7) ? (TT - 1) : 64 * (seg + 1);
        for (int p = pend; p > 64 * seg; --p) {
            const int i = p - 1;
            const unsigned int word = bp32[(i >> 2) * UU + tg];
            tg = (word >> (8 * (i & 3))) & 255u;
        }
        segmap[seg][w & 127] = (unsigned char)tg;
    }
    __syncthreads();

    if (tid == 0) {
        entryT[7] = final_tag_s;
        for (int s = 6; s >= 0; --s) entryT[s] = segmap[s + 1][entryT[s + 1]];
    }
    __syncthreads();

    if (tid < 8) {
        const int seg = tid;
        int tg = entryT[seg];
        const int pend = (seg == 7) ? (TT - 1) : 64 * (seg + 1);
        if (seg == 7) tags_i[TT - 1] = tg;
        for (int p = pend; p > 64 * seg; --p) {
            const int i = p - 1;
            const unsigned int word = bp32[(i >> 2) * UU + tg];
            tg = (word >> (8 * (i & 3))) & 255u;
            tags_i[i] = tg;
        }
    }
    __syncthreads();

    out[(size_t)b * TT + tid] = (float)tags_i[tid];
}

extern "C" void kernel_launch(void* const* d_in, const int* in_sizes, int n_in,
                              void* d_out, int out_size, void* d_ws, size_t ws_size,
                              hipStream_t stream) {
    const float* inputs = (const float*)d_in[0];
    const float* kern   = (const float*)d_in[1];
    const float* bias   = (const float*)d_in[2];
    const float* chain  = (const float*)d_in[3];
    float* logits = (float*)d_ws;   // 16.78 MB scratch
    float* out    = (float*)d_out;

    gemm_kernel<<<dim3((BB * TT) / 128), dim3(256), 0, stream>>>(inputs, kern, bias, logits);
    viterbi_kernel<<<dim3(BB), dim3(512), 0, stream>>>(logits, chain, out);
}

// Round 4
// 467.142 us; speedup vs baseline: 1.4062x; 1.0482x over previous
//
#include <hip/hip_runtime.h>

#define BB 64
#define TT 512
#define DD 1024
#define UU 128

// ---------------------------------------------------------------------------
// Kernel 1: logits = inputs(32768x1024) @ kernel(1024x128) + bias   (fp32)
// 256 blocks x 256 threads, tile 128x128, BK=32, 8x8/thread, reg double-buffer.
// ---------------------------------------------------------------------------
__global__ __launch_bounds__(256) void gemm_kernel(const float* __restrict__ A,
                                                   const float* __restrict__ W,
                                                   const float* __restrict__ bias,
                                                   float* __restrict__ C) {
    __shared__ float As[32][132];
    __shared__ float Ws[32][132];

    const int tid = threadIdx.x;
    const int my = tid >> 4;
    const int nx = tid & 15;
    const int row0 = blockIdx.x * 128;

    const int sc = tid & 7;
    const int sr = tid >> 3;
    const int wn = (tid & 31) * 4;
    const int wk = tid >> 5;

    float acc[8][8] = {};
    float4 pa[4], pw[4];

#define GLOAD(k0)                                                                 \
    {                                                                             \
        _Pragma("unroll")                                                         \
        for (int p = 0; p < 4; ++p)                                               \
            pa[p] = *(const float4*)&A[(size_t)(row0 + sr + p * 32) * DD + (k0) + sc * 4]; \
        _Pragma("unroll")                                                         \
        for (int q = 0; q < 4; ++q)                                               \
            pw[q] = *(const float4*)&W[(size_t)((k0) + wk + 8 * q) * UU + wn];    \
    }

#define GSTORE_LDS                                                                \
    {                                                                             \
        _Pragma("unroll")                                                         \
        for (int p = 0; p < 4; ++p) {                                             \
            const int r = sr + p * 32;                                            \
            As[sc * 4 + 0][r] = pa[p].x;                                          \
            As[sc * 4 + 1][r] = pa[p].y;                                          \
            As[sc * 4 + 2][r] = pa[p].z;                                          \
            As[sc * 4 + 3][r] = pa[p].w;                                          \
        }                                                                         \
        _Pragma("unroll")                                                         \
        for (int q = 0; q < 4; ++q)                                               \
            *(float4*)&Ws[wk + 8 * q][wn] = pw[q];                                \
    }

#define GCOMPUTE                                                                  \
    {                                                                             \
        _Pragma("unroll 8")                                                       \
        for (int k = 0; k < 32; ++k) {                                            \
            const float4 av0 = *(const float4*)&As[k][my * 8];                    \
            const float4 av1 = *(const float4*)&As[k][my * 8 + 4];                \
            const float4 wv0 = *(const float4*)&Ws[k][nx * 8];                    \
            const float4 wv1 = *(const float4*)&Ws[k][nx * 8 + 4];                \
            const float a[8] = {av0.x, av0.y, av0.z, av0.w, av1.x, av1.y, av1.z, av1.w}; \
            const float w[8] = {wv0.x, wv0.y, wv0.z, wv0.w, wv1.x, wv1.y, wv1.z, wv1.w}; \
            _Pragma("unroll")                                                     \
            for (int i = 0; i < 8; ++i)                                           \
                _Pragma("unroll")                                                 \
                for (int j = 0; j < 8; ++j) acc[i][j] = fmaf(a[i], w[j], acc[i][j]); \
        }                                                                         \
    }

    GLOAD(0);
    GSTORE_LDS;
    __syncthreads();
    for (int k0 = 32; k0 < DD; k0 += 32) {
        GLOAD(k0);        // next tile -> regs; lands during compute below
        GCOMPUTE;
        __syncthreads();
        GSTORE_LDS;
        __syncthreads();
    }
    GCOMPUTE;

    const float4 b0 = *(const float4*)&bias[nx * 8];
    const float4 b1 = *(const float4*)&bias[nx * 8 + 4];
#pragma unroll
    for (int i = 0; i < 8; ++i) {
        const int row = row0 + my * 8 + i;
        float4 o0, o1;
        o0.x = acc[i][0] + b0.x; o0.y = acc[i][1] + b0.y;
        o0.z = acc[i][2] + b0.z; o0.w = acc[i][3] + b0.w;
        o1.x = acc[i][4] + b1.x; o1.y = acc[i][5] + b1.y;
        o1.z = acc[i][6] + b1.z; o1.w = acc[i][7] + b1.w;
        *(float4*)&C[(size_t)row * UU + nx * 8] = o0;
        *(float4*)&C[(size_t)row * UU + nx * 8 + 4] = o1;
    }
}

// ---------------------------------------------------------------------------
// Kernel 2: Viterbi. One block (512 threads) per batch.
// tid -> (u = tid>>2, h = tid&3), 32 v per lane. All potentials staged through
// a 64-step LDS ring refilled 32 steps ahead -> no global load drains on the
// per-step barrier. DPP quad_perm merges (strict >, valid for the h0 lane).
// ---------------------------------------------------------------------------
__device__ __forceinline__ int SP(int v) { return v + ((v >> 5) << 2); }

#define QPI(x, ctrl) __builtin_amdgcn_mov_dpp((x), (ctrl), 0xF, 0xF, true)
#define QPF(x, ctrl) __int_as_float(QPI(__float_as_int(x), (ctrl)))

__global__ __launch_bounds__(512) void viterbi_kernel(const float* __restrict__ logits,
                                                      const float* __restrict__ chain,
                                                      float* __restrict__ out) {
    __shared__ __align__(16) float st[2][144];
    __shared__ __align__(16) float pot_lds[64][UU];   // 32 KB ring
    __shared__ unsigned int bp32[128 * UU];           // 64 KB
    __shared__ unsigned char segmap[8][128];
    __shared__ int entryT[8];
    __shared__ int tags_i[TT];
    __shared__ int final_tag_s;

    const int b = blockIdx.x;
    const int tid = threadIdx.x;
    const int u = tid >> 2;
    const int h = tid & 3;

    float cr[32];
#pragma unroll
    for (int j = 0; j < 32; ++j) cr[j] = chain[(size_t)(32 * h + j) * UU + u];

    const float* lg = logits + (size_t)b * TT * UU;
    const float4* lg4 = (const float4*)lg;
    float4* pot4 = (float4*)pot_lds;

    // prologue: pots for steps 0..63 + state init
#pragma unroll
    for (int f = tid; f < 2048; f += 512) pot4[f] = lg4[f];
    if (tid < UU) st[0][SP(tid)] = lg[tid];
    __syncthreads();

    unsigned int bpw = 0;

#define STEP(tt, SRC, DST)                                                        \
    {                                                                             \
        if ((((tt) & 31) == 0) && ((tt) + 32 < TT)) {                             \
            const int f0 = (((tt) + 32) << 5) + tid * 2;                          \
            pot4[f0 & 2047] = lg4[f0];                                            \
            pot4[(f0 + 1) & 2047] = lg4[f0 + 1];                                  \
        }                                                                         \
        const float pot = pot_lds[(tt) & 63][u];                                  \
        const float* sb = &st[SRC][36 * h];                                       \
        float s[32];                                                              \
        _Pragma("unroll")                                                         \
        for (int q = 0; q < 8; ++q) {                                             \
            const float4 sv = *(const float4*)&sb[4 * q];                         \
            s[4 * q + 0] = sv.x + cr[4 * q + 0];                                  \
            s[4 * q + 1] = sv.y + cr[4 * q + 1];                                  \
            s[4 * q + 2] = sv.z + cr[4 * q + 2];                                  \
            s[4 * q + 3] = sv.w + cr[4 * q + 3];                                  \
        }                                                                         \
        float bv0 = s[0], bv1 = s[8], bv2 = s[16], bv3 = s[24];                   \
        int ba0 = 0, ba1 = 8, ba2 = 16, ba3 = 24;                                 \
        _Pragma("unroll")                                                         \
        for (int i = 1; i < 8; ++i) {                                             \
            const bool g0 = s[i] > bv0;      bv0 = g0 ? s[i] : bv0;      ba0 = g0 ? i : ba0;          \
            const bool g1 = s[8 + i] > bv1;  bv1 = g1 ? s[8 + i] : bv1;  ba1 = g1 ? 8 + i : ba1;      \
            const bool g2 = s[16 + i] > bv2; bv2 = g2 ? s[16 + i] : bv2; ba2 = g2 ? 16 + i : ba2;     \
            const bool g3 = s[24 + i] > bv3; bv3 = g3 ? s[24 + i] : bv3; ba3 = g3 ? 24 + i : ba3;     \
        }                                                                         \
        const bool gA = bv1 > bv0; const float bvA = gA ? bv1 : bv0; const int baA = gA ? ba1 : ba0;  \
        const bool gB = bv3 > bv2; const float bvB = gB ? bv3 : bv2; const int baB = gB ? ba3 : ba2;  \
        const bool gC = bvB > bvA; float best = gC ? bvB : bvA;                   \
        int arg = (gC ? baB : baA) + 32 * h;                                      \
        {                                                                         \
            const float ov = QPF(best, 0xB1); const int oa = QPI(arg, 0xB1);      \
            const bool tk = ov > best; best = tk ? ov : best; arg = tk ? oa : arg; \
        }                                                                         \
        {                                                                         \
            const float ov = QPF(best, 0x4E); const int oa = QPI(arg, 0x4E);      \
            const bool tk = ov > best; best = tk ? ov : best; arg = tk ? oa : arg; \
        }                                                                         \
        if (h == 0) {                                                             \
            st[DST][SP(u)] = pot + best;                                          \
            bpw |= (unsigned int)arg << (8 * (((tt) - 1) & 3));                   \
            if ((((tt) - 1) & 3) == 3) {                                          \
                bp32[(((tt) - 1) >> 2) * UU + u] = bpw;                           \
                bpw = 0;                                                          \
            }                                                                     \
        }                                                                         \
        __syncthreads();                                                          \
    }

    for (int t = 1; t < TT - 1; t += 2) {
        STEP(t, 0, 1);
        STEP(t + 1, 1, 0);
    }
    STEP(TT - 1, 0, 1);   // t=511 reads st[0], writes st[1]

    if (h == 0) bp32[127 * UU + u] = bpw;   // transitions 508..510

    // final argmax over st[1] (tie -> lowest index), first wave only
    if (tid < 64) {
        float bv = st[1][SP(tid)];
        int bi = tid;
        const float v2 = st[1][SP(tid + 64)];
        if (v2 > bv) { bv = v2; bi = tid + 64; }
#pragma unroll
        for (int d = 1; d < 64; d <<= 1) {
            const float ov = __shfl_xor(bv, d, 64);
            const int oi = __shfl_xor(bi, d, 64);
            if (ov > bv || (ov == bv && oi < bi)) { bv = ov; bi = oi; }
        }
        if (tid == 0) final_tag_s = bi;
    }
    __syncthreads();

    // ---- segmented backtrace: 8 segments of <=64 transitions ----
    for (int w = tid; w < 8 * 128; w += 512) {
        const int seg = w >> 7;
        int tg = w & 127;
        const int pend = (seg == 7) ? (TT - 1) : 64 * (seg + 1);
        for (int p = pend; p > 64 * seg; --p) {
            const int i = p - 1;
            const unsigned int word = bp32[(i >> 2) * UU + tg];
            tg = (word >> (8 * (i & 3))) & 255u;
        }
        segmap[seg][w & 127] = (unsigned char)tg;
    }
    __syncthreads();

    if (tid == 0) {
        entryT[7] = final_tag_s;
        for (int s = 6; s >= 0; --s) entryT[s] = segmap[s + 1][entryT[s + 1]];
    }
    __syncthreads();

    if (tid < 8) {
        const int seg = tid;
        int tg = entryT[seg];
        const int pend = (seg == 7) ? (TT - 1) : 64 * (seg + 1);
        if (seg == 7) tags_i[TT - 1] = tg;
        for (int p = pend; p > 64 * seg; --p) {
            const int i = p - 1;
            const unsigned int word = bp32[(i >> 2) * UU + tg];
            tg = (word >> (8 * (i & 3))) & 255u;
            tags_i[i] = tg;
        }
    }
    __syncthreads();

    out[(size_t)b * TT + tid] = (float)tags_i[tid];
}

extern "C" void kernel_launch(void* const* d_in, const int* in_sizes, int n_in,
                              void* d_out, int out_size, void* d_ws, size_t ws_size,
                              hipStream_t stream) {
    const float* inputs = (const float*)d_in[0];
    const float* kern   = (const float*)d_in[1];
    const float* bias   = (const float*)d_in[2];
    const float* chain  = (const float*)d_in[3];
    float* logits = (float*)d_ws;   // 16.78 MB scratch
    float* out    = (float*)d_out;

    gemm_kernel<<<dim3((BB * TT) / 128), dim3(256), 0, stream>>>(inputs, kern, bias, logits);
    viterbi_kernel<<<dim3(BB), dim3(512), 0, stream>>>(logits, chain, out);
}

// Round 5
// 457.085 us; speedup vs baseline: 1.4371x; 1.0220x over previous
//
#include <hip/hip_runtime.h>

#define BB 64
#define TT 512
#define DD 1024
#define UU 128

// ---------------------------------------------------------------------------
// Kernel 1: logits = inputs(32768x1024) @ kernel(1024x128) + bias   (fp32)
// R2-proven config: 512 blocks x 256 threads, tile 64x128, BK=64, 4x8/thread.
// ---------------------------------------------------------------------------
#define GBM 64
#define GBK 64

__global__ __launch_bounds__(256) void gemm_kernel(const float* __restrict__ A,
                                                   const float* __restrict__ W,
                                                   const float* __restrict__ bias,
                                                   float* __restrict__ C) {
    __shared__ __align__(16) float As[GBK][GBM + 4];  // k-major, padded
    __shared__ __align__(16) float Ws[GBK][UU];       // k-major

    const int tid = threadIdx.x;
    const int mi = tid >> 4;   // 0..15
    const int ni = tid & 15;   // 0..15
    const int row0 = blockIdx.x * GBM;

    float acc[4][8];
#pragma unroll
    for (int i = 0; i < 4; ++i)
#pragma unroll
        for (int j = 0; j < 8; ++j) acc[i][j] = 0.0f;

    for (int k0 = 0; k0 < DD; k0 += GBK) {
        {
            const int c_ = tid & 15;
            const int r_ = tid >> 4;
#pragma unroll
            for (int p = 0; p < 4; ++p) {
                const int r = r_ + p * 16;
                const float4 a4 = *(const float4*)&A[(size_t)(row0 + r) * DD + k0 + c_ * 4];
                As[c_ * 4 + 0][r] = a4.x;
                As[c_ * 4 + 1][r] = a4.y;
                As[c_ * 4 + 2][r] = a4.z;
                As[c_ * 4 + 3][r] = a4.w;
            }
            const int n4 = (tid & 31) * 4;
            const int kk = tid >> 5;
#pragma unroll
            for (int q = 0; q < 8; ++q) {
                *(float4*)&Ws[kk + q * 8][n4] =
                    *(const float4*)&W[(size_t)(k0 + kk + q * 8) * UU + n4];
            }
        }
        __syncthreads();

#pragma unroll 8
        for (int k = 0; k < GBK; ++k) {
            const float4 av = *(const float4*)&As[k][mi * 4];
            const float4 w0 = *(const float4*)&Ws[k][ni * 8];
            const float4 w1 = *(const float4*)&Ws[k][ni * 8 + 4];
            const float a[4] = {av.x, av.y, av.z, av.w};
            const float w[8] = {w0.x, w0.y, w0.z, w0.w, w1.x, w1.y, w1.z, w1.w};
#pragma unroll
            for (int i = 0; i < 4; ++i)
#pragma unroll
                for (int j = 0; j < 8; ++j) acc[i][j] = fmaf(a[i], w[j], acc[i][j]);
        }
        __syncthreads();
    }

    const float4 b0 = *(const float4*)&bias[ni * 8];
    const float4 b1 = *(const float4*)&bias[ni * 8 + 4];
#pragma unroll
    for (int i = 0; i < 4; ++i) {
        const int row = row0 + mi * 4 + i;
        float4 o0, o1;
        o0.x = acc[i][0] + b0.x; o0.y = acc[i][1] + b0.y;
        o0.z = acc[i][2] + b0.z; o0.w = acc[i][3] + b0.w;
        o1.x = acc[i][4] + b1.x; o1.y = acc[i][5] + b1.y;
        o1.z = acc[i][6] + b1.z; o1.w = acc[i][7] + b1.w;
        *(float4*)&C[(size_t)row * UU + ni * 8] = o0;
        *(float4*)&C[(size_t)row * UU + ni * 8 + 4] = o1;
    }
}

// ---------------------------------------------------------------------------
// Kernel 2: Viterbi. One block (1024 threads, 16 waves = 4/SIMD) per batch.
// tid -> (u = tid>>3, h = tid&7), 16 v per lane. Cross-h merge: 2 DPP
// quad_perm levels + 1 shfl_xor(4). Strided conflict-free pot refill.
// Backpointers packed 4/u32 in LDS; segmented parallel backtrace (8x64).
// ---------------------------------------------------------------------------
__device__ __forceinline__ int SP(int v) { return v + ((v >> 5) << 2); }

#define QPI(x, ctrl) __builtin_amdgcn_mov_dpp((x), (ctrl), 0xF, 0xF, true)
#define QPF(x, ctrl) __int_as_float(QPI(__float_as_int(x), (ctrl)))

__global__ __launch_bounds__(1024) void viterbi_kernel(const float* __restrict__ logits,
                                                       const float* __restrict__ chain,
                                                       float* __restrict__ out) {
    __shared__ __align__(16) float st[2][144];
    __shared__ __align__(16) float pot_lds[64][UU];   // 32 KB ring
    __shared__ unsigned int bp32[128 * UU];           // 64 KB
    __shared__ unsigned char segmap[8][128];
    __shared__ int entryT[8];
    __shared__ int tags_i[TT];
    __shared__ int final_tag_s;

    const int b = blockIdx.x;
    const int tid = threadIdx.x;
    const int u = tid >> 3;    // 0..127
    const int h = tid & 7;     // 0..7, v-range [16h, 16h+16)

    float cr[16];
#pragma unroll
    for (int j = 0; j < 16; ++j) cr[j] = chain[(size_t)(16 * h + j) * UU + u];

    const float* lg = logits + (size_t)b * TT * UU;
    const float4* lg4 = (const float4*)lg;
    float4* pot4 = (float4*)pot_lds;

    // prologue: pots for steps 0..63 + state init
#pragma unroll
    for (int f = tid; f < 2048; f += 1024) pot4[f] = lg4[f];
    if (tid < UU) st[0][SP(tid)] = lg[tid];
    __syncthreads();

    unsigned int bpw = 0;

#define STEP(tt, SRC, DST)                                                        \
    {                                                                             \
        if ((((tt) & 31) == 1) && ((tt) + 31 < TT)) {                             \
            const int f0 = ((tt) + 31) * 32 + tid; /* 1024 consecutive float4s */ \
            pot4[f0 & 2047] = lg4[f0];                                            \
        }                                                                         \
        const float* sb = &st[SRC][16 * h + ((h >> 1) << 2)];                     \
        float s[16];                                                              \
        _Pragma("unroll")                                                         \
        for (int q = 0; q < 4; ++q) {                                             \
            const float4 sv = *(const float4*)&sb[4 * q];                         \
            s[4 * q + 0] = sv.x + cr[4 * q + 0];                                  \
            s[4 * q + 1] = sv.y + cr[4 * q + 1];                                  \
            s[4 * q + 2] = sv.z + cr[4 * q + 2];                                  \
            s[4 * q + 3] = sv.w + cr[4 * q + 3];                                  \
        }                                                                         \
        float bv0 = s[0], bv1 = s[8];                                             \
        int ba0 = 0, ba1 = 8;                                                     \
        _Pragma("unroll")                                                         \
        for (int i = 1; i < 8; ++i) {                                             \
            const bool g0 = s[i] > bv0;     bv0 = g0 ? s[i] : bv0;     ba0 = g0 ? i : ba0;         \
            const bool g1 = s[8 + i] > bv1; bv1 = g1 ? s[8 + i] : bv1; ba1 = g1 ? 8 + i : ba1;     \
        }                                                                         \
        const bool gA = bv1 > bv0;                                                \
        float best = gA ? bv1 : bv0;                                              \
        int arg = (gA ? ba1 : ba0) + 16 * h;                                      \
        {                                                                         \
            const float ov = QPF(best, 0xB1); const int oa = QPI(arg, 0xB1);      \
            const bool tk = ov > best; best = tk ? ov : best; arg = tk ? oa : arg; \
        }                                                                         \
        {                                                                         \
            const float ov = QPF(best, 0x4E); const int oa = QPI(arg, 0x4E);      \
            const bool tk = ov > best; best = tk ? ov : best; arg = tk ? oa : arg; \
        }                                                                         \
        {                                                                         \
            const float ov = __shfl_xor(best, 4, 64); const int oa = __shfl_xor(arg, 4, 64); \
            const bool tk = ov > best; best = tk ? ov : best; arg = tk ? oa : arg; \
        }                                                                         \
        if (h == 0) {                                                             \
            const float pot = pot_lds[(tt) & 63][u];                              \
            st[DST][SP(u)] = pot + best;                                          \
            bpw |= (unsigned int)arg << (8 * (((tt) - 1) & 3));                   \
            if ((((tt) - 1) & 3) == 3) {                                          \
                bp32[(((tt) - 1) >> 2) * UU + u] = bpw;                           \
                bpw = 0;                                                          \
            }                                                                     \
        }                                                                         \
        __syncthreads();                                                          \
    }

    for (int t = 1; t < TT - 1; t += 2) {
        STEP(t, 0, 1);
        STEP(t + 1, 1, 0);
    }
    STEP(TT - 1, 0, 1);   // t=511 reads st[0], writes st[1]

    if (h == 0) bp32[127 * UU + u] = bpw;   // transitions 508..510

    // final argmax over st[1] (tie -> lowest index), first wave only
    if (tid < 64) {
        float bv = st[1][SP(tid)];
        int bi = tid;
        const float v2 = st[1][SP(tid + 64)];
        if (v2 > bv) { bv = v2; bi = tid + 64; }
#pragma unroll
        for (int d = 1; d < 64; d <<= 1) {
            const float ov = __shfl_xor(bv, d, 64);
            const int oi = __shfl_xor(bi, d, 64);
            if (ov > bv || (ov == bv && oi < bi)) { bv = ov; bi = oi; }
        }
        if (tid == 0) final_tag_s = bi;
    }
    __syncthreads();

    // ---- segmented backtrace: 8 segments of <=64 transitions ----
    {
        const int seg = tid >> 7;      // 1024 threads = exactly 8x128 walks
        int tg = tid & 127;
        const int pend = (seg == 7) ? (TT - 1) : 64 * (seg + 1);
        for (int p = pend; p > 64 * seg; --p) {
            const int i = p - 1;
            const unsigned int word = bp32[(i >> 2) * UU + tg];
            tg = (word >> (8 * (i & 3))) & 255u;
        }
        segmap[seg][tid & 127] = (unsigned char)tg;
    }
    __syncthreads();

    if (tid == 0) {
        entryT[7] = final_tag_s;
        for (int s = 6; s >= 0; --s) entryT[s] = segmap[s + 1][entryT[s + 1]];
    }
    __syncthreads();

    if (tid < 8) {
        const int seg = tid;
        int tg = entryT[seg];
        const int pend = (seg == 7) ? (TT - 1) : 64 * (seg + 1);
        if (seg == 7) tags_i[TT - 1] = tg;
        for (int p = pend; p > 64 * seg; --p) {
            const int i = p - 1;
            const unsigned int word = bp32[(i >> 2) * UU + tg];
            tg = (word >> (8 * (i & 3))) & 255u;
            tags_i[i] = tg;
        }
    }
    __syncthreads();

    if (tid < TT) out[(size_t)b * TT + tid] = (float)tags_i[tid];
}

extern "C" void kernel_launch(void* const* d_in, const int* in_sizes, int n_in,
                              void* d_out, int out_size, void* d_ws, size_t ws_size,
                              hipStream_t stream) {
    const float* inputs = (const float*)d_in[0];
    const float* kern   = (const float*)d_in[1];
    const float* bias   = (const float*)d_in[2];
    const float* chain  = (const float*)d_in[3];
    float* logits = (float*)d_ws;   // 16.78 MB scratch
    float* out    = (float*)d_out;

    gemm_kernel<<<dim3((BB * TT) / GBM), dim3(256), 0, stream>>>(inputs, kern, bias, logits);
    viterbi_kernel<<<dim3(BB), dim3(1024), 0, stream>>>(logits, chain, out);
}

// Round 7
// 425.394 us; speedup vs baseline: 1.5442x; 1.0745x over previous
//
#include <hip/hip_runtime.h>

#define BB 64
#define TT 512
#define DD 1024
#define UU 128

// ---------------------------------------------------------------------------
// Kernel 1: logits = inputs(32768x1024) @ kernel(1024x128) + bias   (fp32)
// R2-proven config: 512 blocks x 256 threads, tile 64x128, BK=64, 4x8/thread.
// ---------------------------------------------------------------------------
#define GBM 64
#define GBK 64

__global__ __launch_bounds__(256) void gemm_kernel(const float* __restrict__ A,
                                                   const float* __restrict__ W,
                                                   const float* __restrict__ bias,
                                                   float* __restrict__ C) {
    __shared__ __align__(16) float As[GBK][GBM + 4];  // k-major, padded
    __shared__ __align__(16) float Ws[GBK][UU];       // k-major

    const int tid = threadIdx.x;
    const int mi = tid >> 4;   // 0..15
    const int ni = tid & 15;   // 0..15
    const int row0 = blockIdx.x * GBM;

    float acc[4][8];
#pragma unroll
    for (int i = 0; i < 4; ++i)
#pragma unroll
        for (int j = 0; j < 8; ++j) acc[i][j] = 0.0f;

    for (int k0 = 0; k0 < DD; k0 += GBK) {
        {
            const int c_ = tid & 15;
            const int r_ = tid >> 4;
#pragma unroll
            for (int p = 0; p < 4; ++p) {
                const int r = r_ + p * 16;
                const float4 a4 = *(const float4*)&A[(size_t)(row0 + r) * DD + k0 + c_ * 4];
                As[c_ * 4 + 0][r] = a4.x;
                As[c_ * 4 + 1][r] = a4.y;
                As[c_ * 4 + 2][r] = a4.z;
                As[c_ * 4 + 3][r] = a4.w;
            }
            const int n4 = (tid & 31) * 4;
            const int kk = tid >> 5;
#pragma unroll
            for (int q = 0; q < 8; ++q) {
                *(float4*)&Ws[kk + q * 8][n4] =
                    *(const float4*)&W[(size_t)(k0 + kk + q * 8) * UU + n4];
            }
        }
        __syncthreads();

#pragma unroll 8
        for (int k = 0; k < GBK; ++k) {
            const float4 av = *(const float4*)&As[k][mi * 4];
            const float4 w0 = *(const float4*)&Ws[k][ni * 8];
            const float4 w1 = *(const float4*)&Ws[k][ni * 8 + 4];
            const float a[4] = {av.x, av.y, av.z, av.w};
            const float w[8] = {w0.x, w0.y, w0.z, w0.w, w1.x, w1.y, w1.z, w1.w};
#pragma unroll
            for (int i = 0; i < 4; ++i)
#pragma unroll
                for (int j = 0; j < 8; ++j) acc[i][j] = fmaf(a[i], w[j], acc[i][j]);
        }
        __syncthreads();
    }

    const float4 b0 = *(const float4*)&bias[ni * 8];
    const float4 b1 = *(const float4*)&bias[ni * 8 + 4];
#pragma unroll
    for (int i = 0; i < 4; ++i) {
        const int row = row0 + mi * 4 + i;
        float4 o0, o1;
        o0.x = acc[i][0] + b0.x; o0.y = acc[i][1] + b0.y;
        o0.z = acc[i][2] + b0.z; o0.w = acc[i][3] + b0.w;
        o1.x = acc[i][4] + b1.x; o1.y = acc[i][5] + b1.y;
        o1.z = acc[i][6] + b1.z; o1.w = acc[i][7] + b1.w;
        *(float4*)&C[(size_t)row * UU + ni * 8] = o0;
        *(float4*)&C[(size_t)row * UU + ni * 8 + 4] = o1;
    }
}

// ---------------------------------------------------------------------------
// DPP helpers (ctrl must be a literal constant)
// ---------------------------------------------------------------------------
#define DPPI(x, ctrl) __builtin_amdgcn_mov_dpp((x), (ctrl), 0xF, 0xF, true)
#define DPPF(x, ctrl) __int_as_float(DPPI(__float_as_int(x), (ctrl)))
// quad_perm xor1 = 0xB1, xor2 = 0x4E, row_shl:4 = 0x104

// state padding: v -> v + 4*(v>>4); chunk bases 16B-aligned, disjoint bank quads.
__device__ __forceinline__ int SP16(int v) { return v + ((v >> 4) << 2); }

// ---------------------------------------------------------------------------
// Kernel 2: value-only Viterbi forward. One block (512 thr) per batch.
// tid -> (g = tid>>3: u-pair {2g,2g+1}, h = tid&7: v-chunk [16h,16h+16)).
// State history written back over the logits buffer (reads lead writes by
// >=30 barrier-separated steps). Pot staged via 64-step LDS ring.
// ---------------------------------------------------------------------------
__global__ __launch_bounds__(512, 2) void viterbi_fwd(float* __restrict__ lgst,
                                                      const float* __restrict__ chain) {
    __shared__ __align__(16) float st[2][160];
    __shared__ __align__(16) float pot_lds[64][UU];   // 32 KB ring
    __shared__ __align__(16) float hist[32][UU];      // 16 KB history staging ring

    const int b = blockIdx.x;
    const int tid = threadIdx.x;
    const int g = tid >> 3;
    const int h = tid & 7;

    float cr0[16], cr1[16];
#pragma unroll
    for (int j = 0; j < 16; ++j) {
        cr0[j] = chain[(size_t)(16 * h + j) * UU + 2 * g];
        cr1[j] = chain[(size_t)(16 * h + j) * UU + 2 * g + 1];
    }

    float* lg = lgst + (size_t)b * TT * UU;
    const float4* lg4 = (const float4*)lg;
    float4* pot4 = (float4*)pot_lds;
    const float4* hist4 = (const float4*)hist;

    // prologue: pot rows 0..63; st[0] = hist row 0 = logits row 0
    for (int f = tid; f < 2048; f += 512) pot4[f] = lg4[f];
    if (tid < UU) {
        const float v = lg[tid];
        st[0][SP16(tid)] = v;
        hist[0][tid] = v;
    }
    __syncthreads();

    auto step = [&](int tt, const float* stS, float* stD) {
        // flush completed 16-row half of the hist ring back to global (over logits)
        if ((tt & 15) == 0) {
            const int r0 = tt - 16;
            ((float4*)&lg[r0 * UU])[tid] = hist4[((r0 & 31) << 5) + tid];
        }
        // refill pot ring 32 rows ahead
        if ((tt & 31) == 1 && tt > 1 && tt + 31 < TT) {
            const int f0 = (tt + 31) * 32 + tid;
            pot4[f0 & 2047] = lg4[f0];
            pot4[(f0 + 512) & 2047] = lg4[f0 + 512];
        }

        const float4* sbp = (const float4*)(stS + 20 * h);
        const float4 sv0 = sbp[0], sv1 = sbp[1], sv2 = sbp[2], sv3 = sbp[3];
        const float a[16] = {sv0.x, sv0.y, sv0.z, sv0.w, sv1.x, sv1.y, sv1.z, sv1.w,
                             sv2.x, sv2.y, sv2.z, sv2.w, sv3.x, sv3.y, sv3.z, sv3.w};
        float s0[16], s1[16];
#pragma unroll
        for (int j = 0; j < 16; ++j) {
            s0[j] = a[j] + cr0[j];
            s1[j] = a[j] + cr1[j];
        }
        float m0, m1;
        {
            float x0 = fmaxf(s0[0], s0[1]), x1 = fmaxf(s0[2], s0[3]);
            float x2 = fmaxf(s0[4], s0[5]), x3 = fmaxf(s0[6], s0[7]);
            float x4 = fmaxf(s0[8], s0[9]), x5 = fmaxf(s0[10], s0[11]);
            float x6 = fmaxf(s0[12], s0[13]), x7 = fmaxf(s0[14], s0[15]);
            m0 = fmaxf(fmaxf(fmaxf(x0, x1), fmaxf(x2, x3)), fmaxf(fmaxf(x4, x5), fmaxf(x6, x7)));
        }
        {
            float x0 = fmaxf(s1[0], s1[1]), x1 = fmaxf(s1[2], s1[3]);
            float x2 = fmaxf(s1[4], s1[5]), x3 = fmaxf(s1[6], s1[7]);
            float x4 = fmaxf(s1[8], s1[9]), x5 = fmaxf(s1[10], s1[11]);
            float x6 = fmaxf(s1[12], s1[13]), x7 = fmaxf(s1[14], s1[15]);
            m1 = fmaxf(fmaxf(fmaxf(x0, x1), fmaxf(x2, x3)), fmaxf(fmaxf(x4, x5), fmaxf(x6, x7)));
        }
        // merge across the 8 h-lanes (value-only fmax: order-independent)
        m0 = fmaxf(m0, DPPF(m0, 0xB1));  m1 = fmaxf(m1, DPPF(m1, 0xB1));
        m0 = fmaxf(m0, DPPF(m0, 0x4E));  m1 = fmaxf(m1, DPPF(m1, 0x4E));
        m0 = fmaxf(m0, DPPF(m0, 0x104)); m1 = fmaxf(m1, DPPF(m1, 0x104));

        if (h < 2) {
            const int u = 2 * g + h;
            const float ns = pot_lds[tt & 63][u] + (h ? m1 : m0);
            stD[SP16(u)] = ns;
            hist[tt & 31][u] = ns;
        }
        __syncthreads();
    };

    for (int t = 1; t < TT - 1; t += 2) {
        step(t, st[0], st[1]);
        step(t + 1, st[1], st[0]);
    }
    step(TT - 1, st[0], st[1]);

    // final flush: rows 496..511 (ring slots 16..31)
    ((float4*)&lg[496 * UU])[tid] = hist4[((496 & 31) << 5) + tid];
}

// ---------------------------------------------------------------------------
// Kernel 3: backpointer recovery — fully parallel over (b, t).
// bp[b][t][u] = argmax_v(st[t-1][v] + chain[v][u]), lowest-v tie-break.
// Grid: 64 batches x 8 t-chunks; block 512 thr, same (g,h) layout.
// ---------------------------------------------------------------------------
#define MERGE2(bv, ba, ctrl)                                                      \
    {                                                                             \
        const float ov_ = DPPF((bv), ctrl); const int oa_ = DPPI((ba), ctrl);     \
        const bool tk_ = (ov_ > (bv)) || (ov_ == (bv) && oa_ < (ba));             \
        (bv) = tk_ ? ov_ : (bv); (ba) = tk_ ? oa_ : (ba);                         \
    }

__global__ __launch_bounds__(512) void bp_kernel(const float* __restrict__ st_g,
                                                 const float* __restrict__ chain,
                                                 unsigned char* __restrict__ bp_g) {
    const int blk = blockIdx.x;
    const int b = blk >> 3;
    const int c = blk & 7;
    const int tid = threadIdx.x;
    const int g = tid >> 3;
    const int h = tid & 7;
    const int base = 16 * h;

    float cr0[16], cr1[16];
#pragma unroll
    for (int j = 0; j < 16; ++j) {
        cr0[j] = chain[(size_t)(base + j) * UU + 2 * g];
        cr1[j] = chain[(size_t)(base + j) * UU + 2 * g + 1];
    }

    const float* stb = st_g + (size_t)b * TT * UU;
    const int t0 = (c == 0) ? 1 : c * 64;
    const int t1 = c * 64 + 64;

    for (int t = t0; t < t1; ++t) {
        const float4* sp = (const float4*)(stb + (size_t)(t - 1) * UU + base);
        const float4 sv0 = sp[0], sv1 = sp[1], sv2 = sp[2], sv3 = sp[3];
        const float a[16] = {sv0.x, sv0.y, sv0.z, sv0.w, sv1.x, sv1.y, sv1.z, sv1.w,
                             sv2.x, sv2.y, sv2.z, sv2.w, sv3.x, sv3.y, sv3.z, sv3.w};

        float bv0, bv1;
        int ba0, ba1;
        {
            float vA = a[0] + cr0[0]; int iA = base;
            float vB = a[8] + cr0[8]; int iB = base + 8;
#pragma unroll
            for (int i = 1; i < 8; ++i) {
                const float tA = a[i] + cr0[i];
                const bool gA = tA > vA; vA = gA ? tA : vA; iA = gA ? base + i : iA;
                const float tB = a[8 + i] + cr0[8 + i];
                const bool gB = tB > vB; vB = gB ? tB : vB; iB = gB ? base + 8 + i : iB;
            }
            const bool gg = vB > vA;   // B covers higher v: strict > keeps lowest
            bv0 = gg ? vB : vA; ba0 = gg ? iB : iA;
        }
        {
            float vA = a[0] + cr1[0]; int iA = base;
            float vB = a[8] + cr1[8]; int iB = base + 8;
#pragma unroll
            for (int i = 1; i < 8; ++i) {
                const float tA = a[i] + cr1[i];
                const bool gA = tA > vA; vA = gA ? tA : vA; iA = gA ? base + i : iA;
                const float tB = a[8 + i] + cr1[8 + i];
                const bool gB = tB > vB; vB = gB ? tB : vB; iB = gB ? base + 8 + i : iB;
            }
            const bool gg = vB > vA;
            bv1 = gg ? vB : vA; ba1 = gg ? iB : iA;
        }
        // 3 DPP merge levels with full tie-break (constant ctrls)
        MERGE2(bv0, ba0, 0xB1);  MERGE2(bv1, ba1, 0xB1);
        MERGE2(bv0, ba0, 0x4E);  MERGE2(bv1, ba1, 0x4E);
        MERGE2(bv0, ba0, 0x104); MERGE2(bv1, ba1, 0x104);

        if (h < 2) {
            const int u = 2 * g + h;
            bp_g[((size_t)b * TT + t) * UU + u] = (unsigned char)(h ? ba1 : ba0);
        }
    }
}

// ---------------------------------------------------------------------------
// Kernel 4: backtrace. 64 blocks x 512 thr; bp staged into LDS, segmented walk.
// ---------------------------------------------------------------------------
__global__ __launch_bounds__(512) void backtrace_kernel(const float* __restrict__ st_g,
                                                        const unsigned char* __restrict__ bp_g,
                                                        float* __restrict__ out) {
    __shared__ unsigned char bp[TT][UU];   // 64 KB
    __shared__ unsigned char segmap[8][128];
    __shared__ int entryT[8];
    __shared__ int tags_i[TT];
    __shared__ int final_tag_s;

    const int b = blockIdx.x;
    const int tid = threadIdx.x;

    {
        const uint4* src = (const uint4*)(bp_g + (size_t)b * TT * UU);
        uint4* dst = (uint4*)bp;
#pragma unroll
        for (int i = 0; i < 8; ++i) dst[tid + 512 * i] = src[tid + 512 * i];
    }
    if (tid < 64) {
        const float* fs = st_g + ((size_t)b * TT + (TT - 1)) * UU;
        float bv = fs[tid];
        int bi = tid;
        const float v2 = fs[tid + 64];
        if (v2 > bv) { bv = v2; bi = tid + 64; }
#pragma unroll
        for (int d = 1; d < 64; d <<= 1) {
            const float ov = __shfl_xor(bv, d, 64);
            const int oi = __shfl_xor(bi, d, 64);
            if (ov > bv || (ov == bv && oi < bi)) { bv = ov; bi = oi; }
        }
        if (tid == 0) final_tag_s = bi;
    }
    __syncthreads();

    for (int w = tid; w < 8 * 128; w += 512) {
        const int seg = w >> 7;
        int tg = w & 127;
        const int pend = (seg == 7) ? (TT - 1) : 64 * (seg + 1);
        for (int p = pend; p > 64 * seg; --p) tg = bp[p][tg];
        segmap[seg][w & 127] = (unsigned char)tg;
    }
    __syncthreads();

    if (tid == 0) {
        entryT[7] = final_tag_s;
        for (int s = 6; s >= 0; --s) entryT[s] = segmap[s + 1][entryT[s + 1]];
    }
    __syncthreads();

    if (tid < 8) {
        const int seg = tid;
        int tg = entryT[seg];
        const int pend = (seg == 7) ? (TT - 1) : 64 * (seg + 1);
        if (seg == 7) tags_i[TT - 1] = tg;
        for (int p = pend; p > 64 * seg; --p) {
            tg = bp[p][tg];
            tags_i[p - 1] = tg;
        }
    }
    __syncthreads();

    out[(size_t)b * TT + tid] = (float)tags_i[tid];
}

extern "C" void kernel_launch(void* const* d_in, const int* in_sizes, int n_in,
                              void* d_out, int out_size, void* d_ws, size_t ws_size,
                              hipStream_t stream) {
    const float* inputs = (const float*)d_in[0];
    const float* kern   = (const float*)d_in[1];
    const float* bias   = (const float*)d_in[2];
    const float* chain  = (const float*)d_in[3];

    float* logits_st = (float*)d_ws;                                     // 16.78 MB (logits -> state history)
    unsigned char* bp = (unsigned char*)d_ws + (size_t)BB * TT * UU * 4; // +4.19 MB
    float* out = (float*)d_out;

    gemm_kernel<<<dim3((BB * TT) / GBM), dim3(256), 0, stream>>>(inputs, kern, bias, logits_st);
    viterbi_fwd<<<dim3(BB), dim3(512), 0, stream>>>(logits_st, chain);
    bp_kernel<<<dim3(BB * 8), dim3(512), 0, stream>>>(logits_st, chain, bp);
    backtrace_kernel<<<dim3(BB), dim3(512), 0, stream>>>(logits_st, bp, out);
}